// Round 5
// baseline (204.560 us; speedup 1.0000x reference)
//
#include <hip/hip_runtime.h>
#include <hip/hip_bf16.h>

// Shapes (fixed by the reference)
#define NB 8
#define ND 512
#define NL 2048
#define NH 8
#define NDH 64
#define VROWS 72   // V head rows: 64 V + 1 mask row + 7 zero rows

typedef __attribute__((ext_vector_type(8))) short bf16x8;
typedef __attribute__((ext_vector_type(4))) float f32x4;
typedef __attribute__((ext_vector_type(4))) unsigned int u32x4;

__device__ __forceinline__ unsigned short f2bf(float x) {
    return (unsigned short)((__float_as_uint(x) + 0x8000u) >> 16);
}

__device__ __forceinline__ float exp2_fast(float x) {
#if __has_builtin(__builtin_amdgcn_exp2f)
    return __builtin_amdgcn_exp2f(x);
#else
    return exp2f(x);
#endif
}

// pack bf16(a) | bf16(b)<<16 : 2 rounding adds + 1 v_perm_b32
__device__ __forceinline__ unsigned int pack_bf16(float a, float b) {
    unsigned int ua = __float_as_uint(a) + 0x8000u;
    unsigned int ub = __float_as_uint(b) + 0x8000u;
    return __builtin_amdgcn_perm(ub, ua, 0x07060302u);
}

// async global->LDS, 16 B per lane; lds base must be wave-uniform,
// lane i lands at lds + i*16.
__device__ __forceinline__ void async16(void* lds, const void* g) {
    __builtin_amdgcn_global_load_lds(
        (const __attribute__((address_space(1))) unsigned int*)g,
        (__attribute__((address_space(3))) unsigned int*)lds, 16, 0, 0);
}

// ---------------------------------------------------------------------------
// convert_w: Wcat bf16 [1536][512] = [w_mem ; w_q * 0.125 * log2(e)].
// ---------------------------------------------------------------------------
__global__ __launch_bounds__(256) void convert_w(
    const float* __restrict__ w_mem, const float* __restrict__ w_q,
    unsigned short* __restrict__ Wc)
{
    int idx = (blockIdx.x * 256 + threadIdx.x) * 8;   // grid 384
    int o = idx >> 9, k = idx & 511;
    const float* src;
    float sc;
    if (o < 1024) { src = w_mem + (size_t)o * ND + k; sc = 1.0f; }
    else          { src = w_q + (size_t)(o - 1024) * ND + k;
                    sc = 0.125f * 1.4426950408889634f; }
    float4 f0 = *(const float4*)src;
    float4 f1 = *(const float4*)(src + 4);
    ushort4 p0 = { f2bf(f0.x * sc), f2bf(f0.y * sc), f2bf(f0.z * sc), f2bf(f0.w * sc) };
    ushort4 p1 = { f2bf(f1.x * sc), f2bf(f1.y * sc), f2bf(f1.z * sc), f2bf(f1.w * sc) };
    *(ushort4*)(Wc + idx) = p0;
    *(ushort4*)(Wc + idx + 4) = p1;
}

// ---------------------------------------------------------------------------
// convert_xt: Xt bf16 [b][l][d]  <-  queries fp32 [b][d][l]  (LDS transpose).
// ---------------------------------------------------------------------------
__global__ __launch_bounds__(256) void convert_xt(
    const float* __restrict__ qin, unsigned short* __restrict__ Xt)
{
    __shared__ __align__(16) unsigned short T[64][72];
    const int b = blockIdx.z, d0 = blockIdx.y * 64, l0 = blockIdx.x * 64;
    const int t = threadIdx.x;
    const float* X = qin + ((size_t)b * ND + d0) * NL + l0;
    #pragma unroll
    for (int i = 0; i < 4; ++i) {
        int e = t + i * 256;
        int d = e >> 4, l4 = (e & 15) * 4;
        float4 v = *(const float4*)(X + (size_t)d * NL + l4);
        T[l4 + 0][d] = f2bf(v.x);
        T[l4 + 1][d] = f2bf(v.y);
        T[l4 + 2][d] = f2bf(v.z);
        T[l4 + 3][d] = f2bf(v.w);
    }
    __syncthreads();
    #pragma unroll
    for (int i = 0; i < 2; ++i) {
        int e = t + i * 256;
        int row = e >> 3, c8 = (e & 7) * 8;
        *(bf16x8*)(Xt + ((size_t)b * NL + l0 + row) * ND + d0 + c8) =
            *(const bf16x8*)&T[row][c8];
    }
}

// ---------------------------------------------------------------------------
// write_vmask: Vt row 64 = key-permuted mask (bf16 1/0), rows 65..71 = 0.
// The mask row makes the PV MFMA compute lsum (sum of unmasked p) for free.
// ---------------------------------------------------------------------------
__global__ __launch_bounds__(256) void write_vmask(
    const int* __restrict__ maskp, unsigned short* __restrict__ Vt)
{
    const int bh = blockIdx.x;            // grid 64: b*8+h
    const int b = bh >> 3;
    unsigned short* base = Vt + (size_t)bh * VROWS * NL;
    unsigned short* row64 = base + (size_t)64 * NL;
    for (int kk = threadIdx.x; kk < NL; kk += 256) {
        int s  = (kk & 32) | ((kk & 12) << 1) | ((kk & 16) >> 2) | (kk & 3);
        int lp = (kk & ~63) | s;
        row64[lp] = maskp[b * NL + kk] ? (unsigned short)0x3F80 : (unsigned short)0;
    }
    unsigned short* z = base + (size_t)65 * NL;
    for (int i = threadIdx.x; i < 7 * NL; i += 256) z[i] = 0;
}

// ---------------------------------------------------------------------------
// proj_mfma: C[o][l] = sum_k Wc[o][k] * Xt[b][l][k].
// Staging via global_load_lds (16 B/lane) into UNPADDED LDS with XOR column
// swizzle: LDS(r, cb') at r*64 + cb'*8 holds source col-block cb = cb'^(r&7).
// Frag reads are <=2-way bank aliased (free). V columns multiplied by mask
// (masked keys' V = 0) and key-permuted within 64-blocks (attention PV
// B-operand = S^T C-layout, registers only).
// ---------------------------------------------------------------------------
__global__ __launch_bounds__(256, 3) void proj_mfma(
    const unsigned short* __restrict__ Wc,
    const unsigned short* __restrict__ Xt,
    const int* __restrict__ maskp,
    unsigned short* __restrict__ Kh,
    unsigned short* __restrict__ Qh,
    unsigned short* __restrict__ Vt)
{
    __shared__ __align__(16) unsigned short As[128 * 64];
    __shared__ __align__(16) unsigned short Bs[128 * 64];

    const int b  = blockIdx.z;
    const int m0 = blockIdx.y * 128;
    const int n0 = blockIdx.x * 128;
    const int t  = threadIdx.x;
    const int w = t >> 6, lane = t & 63, quad = lane >> 4, lq = lane & 15;
    const int wo = (w >> 1) * 64, wl = (w & 1) * 64;
    const int lr = lane >> 3;                 // staging row within 8-row group
    const int cbsw = (lane & 7) ^ lr;         // swizzled source col-block

    f32x4 acc[4][4];
    #pragma unroll
    for (int im = 0; im < 4; ++im)
        #pragma unroll
        for (int in = 0; in < 4; ++in)
            acc[im][in] = (f32x4){0.f, 0.f, 0.f, 0.f};

    for (int k0 = 0; k0 < ND; k0 += 64) {
        __syncthreads();
        #pragma unroll 2
        for (int i = w; i < 32; i += 4) {
            if (i < 16) {
                int R = i * 8;
                async16(&As[R * 64],
                        Wc + (size_t)(m0 + R + lr) * ND + k0 + cbsw * 8);
            } else {
                int R = (i - 16) * 8;
                async16(&Bs[R * 64],
                        Xt + ((size_t)b * NL + n0 + R + lr) * ND + k0 + cbsw * 8);
            }
        }
        __syncthreads();

        #pragma unroll
        for (int ks = 0; ks < 2; ++ks) {
            bf16x8 af[4], bfr[4];
            #pragma unroll
            for (int im = 0; im < 4; ++im) {
                int r = wo + im * 16 + lq;
                af[im] = *(const bf16x8*)&As[r * 64 + (((ks * 4 + quad) ^ (lq & 7)) * 8)];
            }
            #pragma unroll
            for (int in = 0; in < 4; ++in) {
                int r = wl + in * 16 + lq;
                bfr[in] = *(const bf16x8*)&Bs[r * 64 + (((ks * 4 + quad) ^ (lq & 7)) * 8)];
            }
            #pragma unroll
            for (int im = 0; im < 4; ++im)
                #pragma unroll
                for (int in = 0; in < 4; ++in)
                    acc[im][in] = __builtin_amdgcn_mfma_f32_16x16x32_bf16(
                        af[im], bfr[in], acc[im][in], 0, 0, 0);
        }
    }

    const int reg = (m0 + wo) >> 9;   // 0=K, 1=V, 2=Q
    if (reg != 1) {
        unsigned short* dst = (reg == 0) ? Kh : Qh;
        #pragma unroll
        for (int im = 0; im < 4; ++im) {
            int o  = (m0 + wo + im * 16 + quad * 4) & 511;
            int hh = o >> 6, dh = o & 63;
            #pragma unroll
            for (int in = 0; in < 4; ++in) {
                int l = n0 + wl + in * 16 + lq;
                ushort4 pk = { f2bf(acc[im][in][0]), f2bf(acc[im][in][1]),
                               f2bf(acc[im][in][2]), f2bf(acc[im][in][3]) };
                *(ushort4*)&dst[(((size_t)b * NH + hh) * NL + l) * NDH + dh] = pk;
            }
        }
    } else {
        float mv[4];
        #pragma unroll
        for (int in = 0; in < 4; ++in)
            mv[in] = (float)maskp[b * NL + (n0 + wl + in * 16 + lq)];
        #pragma unroll
        for (int im = 0; im < 4; ++im) {
            int o  = (m0 + wo + im * 16 + quad * 4) & 511;
            int hh = o >> 6, dh = o & 63;
            #pragma unroll
            for (int in = 0; in < 4; ++in) {
                int l  = n0 + wl + in * 16 + lq;
                int kk = l & 63;
                int s  = (kk & 32) | ((kk & 12) << 1) | ((kk & 16) >> 2) | (kk & 3);
                int lp = (l & ~63) | s;
                #pragma unroll
                for (int r = 0; r < 4; ++r)
                    Vt[(((size_t)(b * NH + hh)) * VROWS + dh + r) * NL + lp] =
                        f2bf(acc[im][in][r] * mv[in]);
            }
        }
    }
}

// ---------------------------------------------------------------------------
// attn_mfma v3: block = (b, h, 256 q-rows), 4 waves x 64 q-rows.
// Double-buffered LDS K/V staged by async global_load_lds (1 barrier/tile).
// No mask, no lsum VALU: masked V cols are zero; V row 64 (mask row) makes
// the PV MFMA produce lsum in oacc[4]. Softmax = exp2 + v_perm pack only.
// XCD swizzle: blockIdx%8 = h -> all q-tiles of (.,h) share an XCD's L2.
// ---------------------------------------------------------------------------
__global__ __launch_bounds__(256, 2) void attn_mfma(
    const unsigned short* __restrict__ Qh,
    const unsigned short* __restrict__ Kh,
    const unsigned short* __restrict__ Vt,
    float* __restrict__ out)
{
    __shared__ __align__(16) unsigned short Ks2[2][64 * 64];
    __shared__ __align__(16) unsigned short Vs2[2][80 * 64]; // rows 72..79 never staged (outputs discarded)

    const int id = blockIdx.x;
    const int h  = id & 7;
    const int b  = (id >> 3) & 7;
    const int q0 = (id >> 6) * 256;
    const int t = threadIdx.x;
    const int w = t >> 6, lane = t & 63, quad = lane >> 4, lq = lane & 15;
    const int lr = lane >> 3;
    const int cbsw = (lane & 7) ^ lr;

    const unsigned short* Qg = Qh + ((size_t)(b * NH + h)) * NL * NDH;
    const unsigned short* Kg = Kh + ((size_t)(b * NH + h)) * NL * NDH;
    const unsigned short* Vg = Vt + ((size_t)(b * NH + h)) * VROWS * NL;

    // ---- stage tile 0 (async) ----
    #pragma unroll 2
    for (int i = w; i < 17; i += 4) {
        if (i < 8) {
            int R = i * 8;
            async16(&Ks2[0][R * 64], Kg + (size_t)(R + lr) * NDH + cbsw * 8);
        } else {
            int R = (i - 8) * 8;
            async16(&Vs2[0][R * 64], Vg + (size_t)(R + lr) * NL + cbsw * 8);
        }
    }

    // ---- Q fragments straight to registers (overlaps the DMA) ----
    bf16x8 qf[4][2];
    #pragma unroll
    for (int ni = 0; ni < 4; ++ni)
        #pragma unroll
        for (int ks = 0; ks < 2; ++ks)
            qf[ni][ks] = *(const bf16x8*)
                &Qg[(size_t)(q0 + w * 64 + ni * 16 + lq) * NDH + ks * 32 + quad * 8];

    f32x4 oacc[5][4];
    #pragma unroll
    for (int dm = 0; dm < 5; ++dm)
        #pragma unroll
        for (int ni = 0; ni < 4; ++ni)
            oacc[dm][ni] = (f32x4){0.f, 0.f, 0.f, 0.f};

    int cur = 0;
    for (int k0 = 0; k0 < NL; k0 += 64) {
        __syncthreads();   // drains DMA for buf[cur]; frees buf[cur^1]

        if (k0 + 64 < NL) {
            const int kn = k0 + 64, nb = cur ^ 1;
            #pragma unroll 2
            for (int i = w; i < 17; i += 4) {
                if (i < 8) {
                    int R = i * 8;
                    async16(&Ks2[nb][R * 64],
                            Kg + (size_t)(kn + R + lr) * NDH + cbsw * 8);
                } else {
                    int R = (i - 8) * 8;
                    async16(&Vs2[nb][R * 64],
                            Vg + (size_t)(R + lr) * NL + kn + cbsw * 8);
                }
            }
        }

        const unsigned short* KsB = Ks2[cur];
        const unsigned short* VsB = Vs2[cur];

        // ---- S^T = K Q^T (log2 units) ----
        f32x4 sacc[4][4];
        #pragma unroll
        for (int mi = 0; mi < 4; ++mi)
            #pragma unroll
            for (int ni = 0; ni < 4; ++ni)
                sacc[mi][ni] = (f32x4){0.f, 0.f, 0.f, 0.f};
        #pragma unroll
        for (int ks = 0; ks < 2; ++ks) {
            bf16x8 kf[4];
            #pragma unroll
            for (int mi = 0; mi < 4; ++mi)
                kf[mi] = *(const bf16x8*)
                    &KsB[(mi * 16 + lq) * 64 + (((ks * 4 + quad) ^ (lq & 7)) * 8)];
            #pragma unroll
            for (int mi = 0; mi < 4; ++mi)
                #pragma unroll
                for (int ni = 0; ni < 4; ++ni)
                    sacc[mi][ni] = __builtin_amdgcn_mfma_f32_16x16x32_bf16(
                        kf[mi], qf[ni][ks], sacc[mi][ni], 0, 0, 0);
        }

        // ---- p = exp2(s); pack into PV B-fragments (registers only) ----
        u32x4 pfu[4][2];
        #pragma unroll
        for (int mi = 0; mi < 4; ++mi) {
            const int ks = mi >> 1, jp = (mi & 1) * 2;
            #pragma unroll
            for (int ni = 0; ni < 4; ++ni) {
                float e0 = exp2_fast(sacc[mi][ni][0]);
                float e1 = exp2_fast(sacc[mi][ni][1]);
                float e2 = exp2_fast(sacc[mi][ni][2]);
                float e3 = exp2_fast(sacc[mi][ni][3]);
                pfu[ni][ks][jp + 0] = pack_bf16(e0, e1);
                pfu[ni][ks][jp + 1] = pack_bf16(e2, e3);
            }
        }

        // ---- O^T += V^T P^T ; dm=4 row computes lsum via mask row ----
        #pragma unroll
        for (int ks = 0; ks < 2; ++ks) {
            bf16x8 vf[5];
            #pragma unroll
            for (int dm = 0; dm < 5; ++dm)
                vf[dm] = *(const bf16x8*)
                    &VsB[(dm * 16 + lq) * 64 + (((ks * 4 + quad) ^ (lq & 7)) * 8)];
            #pragma unroll
            for (int dm = 0; dm < 5; ++dm)
                #pragma unroll
                for (int ni = 0; ni < 4; ++ni)
                    oacc[dm][ni] = __builtin_amdgcn_mfma_f32_16x16x32_bf16(
                        vf[dm], __builtin_bit_cast(bf16x8, pfu[ni][ks]),
                        oacc[dm][ni], 0, 0, 0);
        }
        cur ^= 1;
    }

    // ---- epilogue: lsum lives in oacc[4][ni][0] on quad-0 lanes ----
    float inv[4];
    #pragma unroll
    for (int ni = 0; ni < 4; ++ni)
        inv[ni] = 1.0f / __shfl(oacc[4][ni][0], lq);

    #pragma unroll
    for (int dm = 0; dm < 4; ++dm)
        #pragma unroll
        for (int ni = 0; ni < 4; ++ni)
            #pragma unroll
            for (int r = 0; r < 4; ++r) {
                int dh = dm * 16 + quad * 4 + r;
                int l  = q0 + w * 64 + ni * 16 + lq;
                out[((size_t)b * ND + h * NDH + dh) * NL + l] =
                    oacc[dm][ni][r] * inv[ni];
            }
}

extern "C" void kernel_launch(void* const* d_in, const int* in_sizes, int n_in,
                              void* d_out, int out_size, void* d_ws, size_t ws_size,
                              hipStream_t stream) {
    const float* queries = (const float*)d_in[0];
    const int*   maskp   = (const int*)d_in[1];
    const float* w_mem   = (const float*)d_in[2];
    const float* w_q     = (const float*)d_in[3];
    float* out = (float*)d_out;

    const size_t headElems  = (size_t)NB * NH * NL * NDH;    // 8.39M
    const size_t vElems     = (size_t)NB * NH * VROWS * NL;  // 9.44M
    unsigned short* Kh = (unsigned short*)d_ws;
    unsigned short* Vt = Kh + headElems;
    unsigned short* Qh = Vt + vElems;
    unsigned short* Wc = Qh + headElems;                     // 1536*512
    unsigned short* Xt = Wc + (size_t)1536 * ND;             // 8*2048*512
    // total ws use: ~71 MB

    convert_w<<<384, 256, 0, stream>>>(w_mem, w_q, Wc);

    dim3 gx(NL / 64, ND / 64, NB);     // (32, 8, 8)
    convert_xt<<<gx, 256, 0, stream>>>(queries, Xt);

    write_vmask<<<NB * NH, 256, 0, stream>>>(maskp, Vt);

    dim3 g1(NL / 128, 1536 / 128, NB); // (16, 12, 8)
    proj_mfma<<<g1, 256, 0, stream>>>(Wc, Xt, maskp, Kh, Qh, Vt);

    attn_mfma<<<512, 256, 0, stream>>>(Qh, Kh, Vt, out);
}